// Round 5
// baseline (396.568 us; speedup 1.0000x reference)
//
#include <hip/hip_runtime.h>
#include <hip/hip_bf16.h>

#define LL 4
#define NN 50000
#define DD 64
#define EE 500000
#define HID 256
#define KDIM 512
#define LN_EPS 1e-5f

typedef __bf16 bf16x8 __attribute__((ext_vector_type(8)));
typedef float f32x16 __attribute__((ext_vector_type(16)));

__device__ __forceinline__ void async16(const void* g, void* l) {
    __builtin_amdgcn_global_load_lds(
        (const __attribute__((address_space(1))) void*)g,
        (__attribute__((address_space(3))) void*)l, 16, 0, 0);
}

// ---------- kernel 1: t[l,n,d] = bf16( tanh( imp_l * h[l,n,d] ) ) ----------
__global__ void tanh_conv(const float* __restrict__ h, __bf16* __restrict__ t) {
    int i = (blockIdx.x * 256 + threadIdx.x) * 8;          // 12.8M elems, 8/thread
    int l = i / (NN * DD);
    float imp = (float)(l + 1) * 0.1f;
    const float4* p = (const float4*)(h + i);
    float4 a = p[0];
    float4 b = p[1];
    float x[8] = {a.x, a.y, a.z, a.w, b.x, b.y, b.z, b.w};
    bf16x8 r;
    #pragma unroll
    for (int j = 0; j < 8; ++j) {
        float e2 = __expf(2.0f * (imp * x[j]));
        r[j] = (__bf16)(1.0f - 2.0f / (e2 + 1.0f));
    }
    *(bf16x8*)(t + i) = r;
}

// ---------- kernel 2: W1 (256x512 f32) -> bf16, layout [kc][q][h][8] ----------
// element (h, k) with k = kc*32 + q*8 + j  ->  w1c[((kc*4+q)*256 + h)*8 + j]
__global__ void w1_conv(const float* __restrict__ w1, __bf16* __restrict__ o) {
    int t = blockIdx.x * 256 + threadIdx.x;                 // 4096 threads
    int kc = t >> 8;
    int h  = t & 255;
    const float4* p = (const float4*)(w1 + h * KDIM + kc * 32);
    #pragma unroll
    for (int qq = 0; qq < 4; ++qq) {
        float4 va = p[2 * qq];
        float4 vb = p[2 * qq + 1];
        bf16x8 r;
        r[0] = (__bf16)va.x; r[1] = (__bf16)va.y; r[2] = (__bf16)va.z; r[3] = (__bf16)va.w;
        r[4] = (__bf16)vb.x; r[5] = (__bf16)vb.y; r[6] = (__bf16)vb.z; r[7] = (__bf16)vb.w;
        *(bf16x8*)(o + ((size_t)(kc * 4 + qq) * 256 + h) * 8) = r;
    }
}

// ---------- epilogue macro for one 32x32 m-tile set (4 nt tiles) ----------
// 32x32x16 C/D layout: col = lane&31 (c32), row = (r&3) + 8*(r>>2) + 4*h32.
// Macro so no pointer to acc arrays is formed (avoids scratch spill, see R2).
#define EPI(ACC, MT)                                                          \
    do {                                                                      \
        float sum[16], sq[16];                                                \
        _Pragma("unroll")                                                     \
        for (int r = 0; r < 16; ++r) { sum[r] = 0.f; sq[r] = 0.f; }           \
        _Pragma("unroll")                                                     \
        for (int nt = 0; nt < 4; ++nt) {                                      \
            _Pragma("unroll")                                                 \
            for (int r = 0; r < 16; ++r) {                                    \
                float v = ACC[nt][r] + b1v[nt];                               \
                sum[r] += v;                                                  \
                sq[r]   = fmaf(v, v, sq[r]);                                  \
            }                                                                 \
        }                                                                     \
        _Pragma("unroll")                                                     \
        for (int m = 1; m < 32; m <<= 1) {                                    \
            _Pragma("unroll")                                                 \
            for (int r = 0; r < 16; ++r) {                                    \
                sum[r] += __shfl_xor(sum[r], m);                              \
                sq[r]  += __shfl_xor(sq[r],  m);                              \
            }                                                                 \
        }                                                                     \
        if (c32 == 0) {                                                       \
            _Pragma("unroll")                                                 \
            for (int r = 0; r < 16; ++r) {                                    \
                exs[wave][MT][h32][r] = sum[r];                               \
                exq[wave][MT][h32][r] = sq[r];                                \
            }                                                                 \
        }                                                                     \
        __syncthreads();                                                      \
        float mu[16], rs[16];                                                 \
        _Pragma("unroll")                                                     \
        for (int r = 0; r < 16; ++r) {                                        \
            float s = sum[r] + exs[wave ^ 1][MT][h32][r];                     \
            float t2 = sq[r] + exq[wave ^ 1][MT][h32][r];                     \
            mu[r] = s * (1.0f / 256.0f);                                      \
            rs[r] = rsqrtf(t2 * (1.0f / 256.0f) - mu[r] * mu[r] + LN_EPS);    \
        }                                                                     \
        float dot[16];                                                        \
        _Pragma("unroll")                                                     \
        for (int r = 0; r < 16; ++r) dot[r] = 0.f;                            \
        _Pragma("unroll")                                                     \
        for (int nt = 0; nt < 4; ++nt) {                                      \
            _Pragma("unroll")                                                 \
            for (int r = 0; r < 16; ++r) {                                    \
                float v = ACC[nt][r] + b1v[nt];                               \
                float y = fmaxf((v - mu[r]) * rs[r] * gv[nt] + btv[nt], 0.f); \
                dot[r] = fmaf(y, wv[nt], dot[r]);                             \
            }                                                                 \
        }                                                                     \
        _Pragma("unroll")                                                     \
        for (int m = 1; m < 32; m <<= 1) {                                    \
            _Pragma("unroll")                                                 \
            for (int r = 0; r < 16; ++r) dot[r] += __shfl_xor(dot[r], m);     \
        }                                                                     \
        if (c32 == 0) {                                                       \
            _Pragma("unroll")                                                 \
            for (int r = 0; r < 16; ++r) exd[wave][MT][h32][r] = dot[r];      \
        }                                                                     \
        __syncthreads();                                                      \
        if (hw == 0 && c32 == 0) {                                            \
            float b3v = b3[0];                                                \
            _Pragma("unroll")                                                 \
            for (int r = 0; r < 16; ++r) {                                    \
                int e = e_base + (MT) * 32 + (r & 3) + 8 * (r >> 2) + 4 * h32;\
                if (e < EE)                                                   \
                    out[e] = dot[r] + exd[wave + 1][MT][h32][r] + b3v;        \
            }                                                                 \
        }                                                                     \
    } while (0)

// ---------- kernel 3: gather + GEMM + LN + ReLU + dot ----------
// WG = 256 threads (4 waves), 128 edges/WG. Wave pair ep = wave>>1 owns 64
// edges (2 m-tiles of 32, MFMA 32x32x16); hw = wave&1 picks 128 of 256 hid
// (4 nt tiles of 32). acc = 8 x f32x16 = 128 regs -> 2 waves/SIMD.
// K-loop: 8 superchunks of K=64 (32 KB B, double-buffered via DMA).
// ~2000 cyc of MFMA between load-issue and the barrier's vmcnt(0) drain
// -> HBM-latency A-gathers (tb is NOT L3-served; R4 FETCH=243MB) are hidden.
__global__ __launch_bounds__(256, 2)
void edge_mlp(const __bf16* __restrict__ tb, const __bf16* __restrict__ w1c,
              const int* __restrict__ src, const int* __restrict__ dst,
              const float* __restrict__ b1, const float* __restrict__ w3,
              const float* __restrict__ b3, const float* __restrict__ gamma,
              const float* __restrict__ beta, float* __restrict__ out) {
    __shared__ __bf16 B_lds[2 * 16384];  // 2 x 32 KB; superchunk = [kcl(2)][q(4)][h(256)][8]
    __shared__ float eb[4 * 256];        // b1 | gamma | beta | w3
    __shared__ float exs[4][2][2][16];   // [wave][mt][h32][r] partial sum
    __shared__ float exq[4][2][2][16];
    __shared__ float exd[4][2][2][16];

    const int tid  = threadIdx.x;
    const int wave = tid >> 6;
    const int lane = tid & 63;
    const int h32  = lane >> 5;
    const int c32  = lane & 31;
    const int ep   = wave >> 1;   // 64-edge group
    const int hw   = wave & 1;    // 128-hid half

    eb[tid]       = b1[tid];
    eb[256 + tid] = gamma[tid];
    eb[512 + tid] = beta[tid];
    eb[768 + tid] = w3[tid];

    const int e_base = blockIdx.x * 128 + ep * 64;
    const int e0 = e_base + c32;
    const int e1 = e_base + 32 + c32;
    const int os0 = ((e0 < EE) ? src[e0] : 0) * DD;
    const int od0 = ((e0 < EE) ? dst[e0] : 0) * DD;
    const int os1 = ((e1 < EE) ? src[e1] : 0) * DD;
    const int od1 = ((e1 < EE) ? dst[e1] : 0) * DD;

    // DMA superchunk 0 (32 KB linear copy, 8x16B per thread)
    #pragma unroll
    for (int j = 0; j < 8; ++j)
        async16(w1c + (j * 256 + tid) * 8, &B_lds[(j * 256 + tid) * 8]);

    // A prefetch superchunk 0 (layer 0, src half): a[mt][ksub], 16B each
    // A-frag (32x32x16): m = lane&31, k = ksub*16 + h32*8 + j
    uint4 a0[4], a1[4];
    #pragma unroll
    for (int ks = 0; ks < 4; ++ks) {
        const __bf16* p = tb + ks * 16 + h32 * 8;
        a0[ks] = *(const uint4*)(p + os0);
        a1[ks] = *(const uint4*)(p + os1);
    }

    f32x16 acc0[4], acc1[4];   // [nt] for m-tile 0 / 1
    #pragma unroll
    for (int i = 0; i < 4; ++i) {
        acc0[i] = (f32x16)(0.f);
        acc1[i] = (f32x16)(0.f);
    }

    __syncthreads();   // superchunk 0 + eb ready

    #pragma unroll
    for (int s = 0; s < 8; ++s) {
        uint4 an0[4], an1[4];
        if (s < 7) {
            // DMA next superchunk into other buffer
            const __bf16* sw = w1c + (s + 1) * 16384;
            __bf16* dl = &B_lds[((s + 1) & 1) * 16384];
            #pragma unroll
            for (int j = 0; j < 8; ++j)
                async16(sw + (j * 256 + tid) * 8, dl + (j * 256 + tid) * 8);
            // A prefetch next superchunk: s -> layer s>>1, half s&1
            const int sn = s + 1;
            const __bf16* plane = tb + (sn >> 1) * (NN * DD);
            const int o0 = (sn & 1) ? od0 : os0;
            const int o1 = (sn & 1) ? od1 : os1;
            #pragma unroll
            for (int ks = 0; ks < 4; ++ks) {
                const __bf16* p = plane + ks * 16 + h32 * 8;
                an0[ks] = *(const uint4*)(p + o0);
                an1[ks] = *(const uint4*)(p + o1);
            }
        }
        // compute on current buffer: 32 MFMAs
        const __bf16* Bb = &B_lds[(s & 1) * 16384 + (hw * 128 + c32) * 8];
        #pragma unroll
        for (int ks = 0; ks < 4; ++ks) {
            bf16x8 af0 = __builtin_bit_cast(bf16x8, a0[ks]);
            bf16x8 af1 = __builtin_bit_cast(bf16x8, a1[ks]);
            const __bf16* Bk = Bb + (ks * 2 + h32) * 2048;
            #pragma unroll
            for (int nt = 0; nt < 4; ++nt) {
                bf16x8 bf = *(const bf16x8*)(Bk + nt * 256);
                acc0[nt] = __builtin_amdgcn_mfma_f32_32x32x16_bf16(af0, bf, acc0[nt], 0, 0, 0);
                acc1[nt] = __builtin_amdgcn_mfma_f32_32x32x16_bf16(af1, bf, acc1[nt], 0, 0, 0);
            }
        }
        __syncthreads();   // all waves done with buffer (s&1); drains DMA + A
        if (s < 7) {
            #pragma unroll
            for (int ks = 0; ks < 4; ++ks) { a0[ks] = an0[ks]; a1[ks] = an1[ks]; }
        }
    }

    // per-lane epilogue constants for this wave's 4 nt columns
    float b1v[4], gv[4], btv[4], wv[4];
    #pragma unroll
    for (int nt = 0; nt < 4; ++nt) {
        int hh = hw * 128 + nt * 32 + c32;
        b1v[nt] = eb[hh];
        gv[nt]  = eb[256 + hh];
        btv[nt] = eb[512 + hh];
        wv[nt]  = eb[768 + hh];
    }
    EPI(acc0, 0);
    EPI(acc1, 1);
}

extern "C" void kernel_launch(void* const* d_in, const int* in_sizes, int n_in,
                              void* d_out, int out_size, void* d_ws, size_t ws_size,
                              hipStream_t stream) {
    const float* h_all  = (const float*)d_in[0];
    const int*   src    = (const int*)  d_in[1];
    const int*   dst    = (const int*)  d_in[2];
    const float* W1     = (const float*)d_in[3];
    const float* b1     = (const float*)d_in[4];
    const float* W3     = (const float*)d_in[5];
    const float* b3     = (const float*)d_in[6];
    const float* gamma2 = (const float*)d_in[7];
    const float* beta2  = (const float*)d_in[8];
    float* out = (float*)d_out;

    __bf16* tb  = (__bf16*)d_ws;                       // 12.8M bf16 = 25.6 MB
    __bf16* w1c = tb + (size_t)LL * NN * DD;           // 131072 bf16 = 256 KB

    tanh_conv<<<6250, 256, 0, stream>>>(h_all, tb);
    w1_conv<<<16, 256, 0, stream>>>(W1, w1c);
    edge_mlp<<<(EE + 127) / 128, 256, 0, stream>>>(tb, w1c, src, dst,
                                                   b1, W3, b3, gamma2, beta2, out);
}